// Round 5
// baseline (617.863 us; speedup 1.0000x reference)
//
#include <hip/hip_runtime.h>

// LSTM-GCN single step from (H=0, C=0).
// Collapsed math: Fg gate dead (C_prev=0), cheb(H,..)=bh, peephole wc[0],wc[1] dead.
//
// R5: eliminate ALL global atomics (R3/R4 showed random-line device atomics cap
// at ~13-22 G line-ops/s with a 64B HBM writeback each). Bucket sort by
// node>>7 with per-tile LDS histograms + LDS-cursor scatter (radix-style),
// then per-bucket LDS segmented reduction for deg and LDS-accumulated gather
// for tx1. Only LDS atomics remain.

#define FDIM 32
#define MAX_N 100000
#define MAX_E 1600000
#define TILE 8192            // edges per tile (256 thr x 32)
#define NB_MAX 784           // buckets: (100000+127)/128 = 782
#define NBLK_MAX 256         // max tiles: 1.6M/8192 = 196

__device__ float g_dinv[MAX_N];
__device__ int   g_tileh[NB_MAX * NBLK_MAX];   // bin-major per-tile counts -> scanned bases
__device__ int   g_blk[1024];                  // scan block sums
__device__ uint2 g_recA[MAX_E];                // src-sorted: {src_local, w_eff bits}
__device__ uint2 g_recB[MAX_E];                // dst-sorted: {src | dst_local<<17, w_eff bits}
__device__ float g_tx1[MAX_N * FDIM];          // L_hat @ x

// ---- pass A: per-tile histogram (bin-major output) --------------------------
__global__ __launch_bounds__(256) void count_kernel(const int* __restrict__ ei,
                                                    int E, int n_nodes, int nblk,
                                                    int NB, int use_dst) {
    __shared__ int hist[NB_MAX];
    for (int i = threadIdx.x; i < NB; i += 256) hist[i] = 0;
    __syncthreads();
    int base = blockIdx.x * TILE;
    int lim  = min(TILE, E - base);
    for (int t = threadIdx.x; t < lim; t += 256) {
        int e = base + t;
        int s = ei[e], d = ei[E + e];
        if ((unsigned)s >= (unsigned)n_nodes || (unsigned)d >= (unsigned)n_nodes) continue;
        int k = (use_dst ? d : s) >> 7;
        atomicAdd(&hist[k], 1);
    }
    __syncthreads();
    for (int i = threadIdx.x; i < NB; i += 256)
        g_tileh[i * nblk + blockIdx.x] = hist[i];
}

// ---- exclusive scan over g_tileh[0..n) --------------------------------------
__global__ __launch_bounds__(256) void scan1_kernel(int n) {
    __shared__ int sh[256];
    int tid = threadIdx.x;
    int base = blockIdx.x * 1024 + tid * 4;
    int v[4];
#pragma unroll
    for (int i = 0; i < 4; ++i) v[i] = (base + i < n) ? g_tileh[base + i] : 0;
    int tsum = v[0] + v[1] + v[2] + v[3];
    sh[tid] = tsum;
    __syncthreads();
    for (int off = 1; off < 256; off <<= 1) {
        int t = (tid >= off) ? sh[tid - off] : 0;
        __syncthreads();
        sh[tid] += t;
        __syncthreads();
    }
    if (tid == 255) g_blk[blockIdx.x] = sh[255];
    int run = sh[tid] - tsum;
#pragma unroll
    for (int i = 0; i < 4; ++i) {
        if (base + i < n) g_tileh[base + i] = run;
        run += v[i];
    }
}

__global__ __launch_bounds__(256) void scan2_kernel(int nb) {   // nb <= 1024
    __shared__ int sh[256];
    int tid = threadIdx.x;
    int base = tid * 4;
    int v[4];
#pragma unroll
    for (int i = 0; i < 4; ++i) v[i] = (base + i < nb) ? g_blk[base + i] : 0;
    int tsum = v[0] + v[1] + v[2] + v[3];
    sh[tid] = tsum;
    __syncthreads();
    for (int off = 1; off < 256; off <<= 1) {
        int t = (tid >= off) ? sh[tid - off] : 0;
        __syncthreads();
        sh[tid] += t;
        __syncthreads();
    }
    int run = sh[tid] - tsum;
#pragma unroll
    for (int i = 0; i < 4; ++i) {
        if (base + i < nb) g_blk[base + i] = run;
        run += v[i];
    }
}

__global__ __launch_bounds__(256) void scan3_kernel(int n) {
    int off = g_blk[blockIdx.x];
    int base = blockIdx.x * 1024 + threadIdx.x * 4;
#pragma unroll
    for (int i = 0; i < 4; ++i)
        if (base + i < n) g_tileh[base + i] += off;
}

// ---- pass C: scatter with LDS cursors (no global atomics) -------------------
__global__ __launch_bounds__(256) void scatter_src_kernel(const int* __restrict__ ei,
                                                          const float* __restrict__ w,
                                                          int E, int n_nodes, int nblk,
                                                          int NB) {
    __shared__ int cur[NB_MAX];
    for (int i = threadIdx.x; i < NB; i += 256)
        cur[i] = g_tileh[i * nblk + blockIdx.x];
    __syncthreads();
    int base = blockIdx.x * TILE;
    int lim  = min(TILE, E - base);
    for (int t = threadIdx.x; t < lim; t += 256) {
        int e = base + t;
        int s = ei[e], d = ei[E + e];
        if ((unsigned)s >= (unsigned)n_nodes || (unsigned)d >= (unsigned)n_nodes) continue;
        float we = (s == d) ? 0.f : w[e];
        int pos = atomicAdd(&cur[s >> 7], 1);   // LDS atomic
        g_recA[pos] = make_uint2((unsigned)(s & 127), __float_as_uint(we));
    }
}

__global__ __launch_bounds__(256) void scatter_dst_kernel(const int* __restrict__ ei,
                                                          const float* __restrict__ w,
                                                          int E, int n_nodes, int nblk,
                                                          int NB) {
    __shared__ int cur[NB_MAX];
    for (int i = threadIdx.x; i < NB; i += 256)
        cur[i] = g_tileh[i * nblk + blockIdx.x];
    __syncthreads();
    int base = blockIdx.x * TILE;
    int lim  = min(TILE, E - base);
    for (int t = threadIdx.x; t < lim; t += 256) {
        int e = base + t;
        int s = ei[e], d = ei[E + e];
        if ((unsigned)s >= (unsigned)n_nodes || (unsigned)d >= (unsigned)n_nodes) continue;
        float we = (s == d) ? 0.f : w[e];
        int pos = atomicAdd(&cur[d >> 7], 1);   // LDS atomic
        g_recB[pos] = make_uint2((unsigned)s | ((unsigned)(d & 127) << 17),
                                 __float_as_uint(we));
    }
}

// ---- per-bucket deg segmented sum + rsqrt (reads src-sorted recs) -----------
__global__ __launch_bounds__(256) void deg_kernel(int E, int n_nodes, int nblk, int NB) {
    __shared__ float degl[128];
    int bin = blockIdx.x;
    int tid = threadIdx.x;
    if (tid < 128) degl[tid] = 0.f;
    __syncthreads();
    int start = g_tileh[bin * nblk];
    int end   = (bin + 1 < NB) ? g_tileh[(bin + 1) * nblk] : E;
    for (int i = start + tid; i < end; i += 256) {
        uint2 r = g_recA[i];
        atomicAdd(&degl[r.x], __uint_as_float(r.y));   // LDS atomic
    }
    __syncthreads();
    if (tid < 128) {
        int node = bin * 128 + tid;
        if (node < n_nodes) {
            float dg = degl[tid];
            g_dinv[node] = (dg > 0.f) ? rsqrtf(dg) : 0.f;
        }
    }
}

// ---- per-bucket gather: tx1 = L_hat @ x (reads dst-sorted recs) -------------
__global__ __launch_bounds__(256) void gather_kernel(const float* __restrict__ x,
                                                     int E, int n_nodes, int nblk,
                                                     int NB) {
    __shared__ float acc[128 * FDIM];   // 16 KB
    int tid = threadIdx.x;
    for (int i = tid; i < 128 * FDIM; i += 256) acc[i] = 0.f;
    __syncthreads();
    int bin = blockIdx.x;
    int start = g_tileh[bin * nblk];
    int end   = (bin + 1 < NB) ? g_tileh[(bin + 1) * nblk] : E;
    int hw = tid >> 5;        // 8 half-waves per block
    int f  = tid & 31;
    int nodeb = bin * 128;
    int i = start + hw;
    for (; i + 24 < end; i += 32) {          // unroll-4: batch loads to hide latency
        uint2 r0 = g_recB[i],      r1 = g_recB[i + 8];
        uint2 r2 = g_recB[i + 16], r3 = g_recB[i + 24];
        int s0 = r0.x & 0x1FFFF, s1 = r1.x & 0x1FFFF;
        int s2 = r2.x & 0x1FFFF, s3 = r3.x & 0x1FFFF;
        float x0 = x[s0 * FDIM + f], x1 = x[s1 * FDIM + f];
        float x2 = x[s2 * FDIM + f], x3 = x[s3 * FDIM + f];
        float n0 = -g_dinv[s0] * __uint_as_float(r0.y) * g_dinv[nodeb + (r0.x >> 17)];
        float n1 = -g_dinv[s1] * __uint_as_float(r1.y) * g_dinv[nodeb + (r1.x >> 17)];
        float n2 = -g_dinv[s2] * __uint_as_float(r2.y) * g_dinv[nodeb + (r2.x >> 17)];
        float n3 = -g_dinv[s3] * __uint_as_float(r3.y) * g_dinv[nodeb + (r3.x >> 17)];
        atomicAdd(&acc[(r0.x >> 17) * FDIM + f], n0 * x0);
        atomicAdd(&acc[(r1.x >> 17) * FDIM + f], n1 * x1);
        atomicAdd(&acc[(r2.x >> 17) * FDIM + f], n2 * x2);
        atomicAdd(&acc[(r3.x >> 17) * FDIM + f], n3 * x3);
    }
    for (; i < end; i += 8) {
        uint2 r = g_recB[i];
        int s = r.x & 0x1FFFF;
        int dl = r.x >> 17;
        float nrm = -g_dinv[s] * __uint_as_float(r.y) * g_dinv[nodeb + dl];
        atomicAdd(&acc[dl * FDIM + f], nrm * x[s * FDIM + f]);
    }
    __syncthreads();
    for (int j = tid; j < 128 * FDIM; j += 256) {
        int node = nodeb + (j >> 5);
        if (node < n_nodes) g_tx1[node * FDIM + (j & 31)] = acc[j];
    }
}

// ---- gates + epilogue (unchanged from R4) -----------------------------------
__global__ __launch_bounds__(256) void gates_kernel(
    const float* __restrict__ x,
    const float* __restrict__ Wx, const float* __restrict__ bx,
    const float* __restrict__ bh, const float* __restrict__ wc,
    const float* __restrict__ bg, const float* __restrict__ lin_w,
    const float* __restrict__ lin_b, float* __restrict__ out, int n_nodes) {
    __shared__ float Ws[3 * 2048];      // gates {i,c,o} x K=2 x 32x32
    __shared__ float xs[8 * FDIM];
    __shared__ float ts[8 * FDIM];

    for (int idx = threadIdx.x; idx < 2048; idx += 256) {
        Ws[idx]          = Wx[0 * 2048 + idx];
        Ws[2048 + idx]   = Wx[2 * 2048 + idx];
        Ws[4096 + idx]   = Wx[3 * 2048 + idx];
    }
    int node0 = blockIdx.x * 8;
    {
        int n = node0 + (threadIdx.x >> 5);
        int f = threadIdx.x & 31;
        if (n < n_nodes) {
            xs[threadIdx.x] = x[n * FDIM + f];
            ts[threadIdx.x] = g_tx1[n * FDIM + f];
        }
    }
    __syncthreads();

    int ln = threadIdx.x >> 5;
    int j  = threadIdx.x & 31;
    int n  = node0 + ln;
    if (n >= n_nodes) return;

    const float* xr = &xs[ln * FDIM];
    const float* tr = &ts[ln * FDIM];
    float acc_i = 0.f, acc_c = 0.f, acc_o = 0.f;
#pragma unroll
    for (int k = 0; k < 32; ++k) {
        float xv = xr[k], tv = tr[k];
        int o0 = k * 32 + j;
        acc_i += xv * Ws[o0]          + tv * Ws[1024 + o0];
        acc_c += xv * Ws[2048 + o0]   + tv * Ws[3072 + o0];
        acc_o += xv * Ws[4096 + o0]   + tv * Ws[5120 + o0];
    }
    float bi = bx[0 * 32 + j] + bh[0 * 32 + j] + bg[0 * 32 + j];
    float bc = bx[2 * 32 + j] + bh[2 * 32 + j] + bg[2 * 32 + j];
    float bo = bx[3 * 32 + j] + bh[3 * 32 + j] + bg[3 * 32 + j];

    float I = 1.f / (1.f + __expf(-(acc_i + bi)));
    float T = tanhf(acc_c + bc);
    float C = I * T;                                    // Fg*C_prev = 0
    float O = 1.f / (1.f + __expf(-(acc_o + bo + wc[2 * 32 + j] * C)));
    float H = O * tanhf(C);
    float r = fmaxf(H, 0.f) * lin_w[j];
#pragma unroll
    for (int m = 16; m > 0; m >>= 1) r += __shfl_xor(r, m, 32);
    if (j == 0) out[n] = r + lin_b[0];
}

extern "C" void kernel_launch(void* const* d_in, const int* in_sizes, int n_in,
                              void* d_out, int out_size, void* d_ws, size_t ws_size,
                              hipStream_t stream) {
    const float* x     = (const float*)d_in[0];
    const int*   ei    = (const int*)d_in[1];      // int32 on device
    const float* w     = (const float*)d_in[2];
    const float* Wx    = (const float*)d_in[3];
    const float* bx    = (const float*)d_in[4];
    // d_in[5] = Wh: unused (H=0)
    const float* bh    = (const float*)d_in[6];
    const float* wc    = (const float*)d_in[7];
    const float* bg    = (const float*)d_in[8];
    const float* lin_w = (const float*)d_in[9];
    const float* lin_b = (const float*)d_in[10];
    float*       out   = (float*)d_out;

    int n_nodes = in_sizes[0] / FDIM;
    if (n_nodes > MAX_N) n_nodes = MAX_N;
    int E = in_sizes[2];
    if (E > MAX_E) E = MAX_E;

    const int nblk = (E + TILE - 1) / TILE;          // 196
    const int NB   = (n_nodes + 127) >> 7;           // 782
    const int n_scan = NB * nblk;                    // 153,272
    const int sb   = (n_scan + 1023) / 1024;         // 150

    // --- sort by src, then segmented deg+rsqrt ---
    count_kernel<<<nblk, 256, 0, stream>>>(ei, E, n_nodes, nblk, NB, 0);
    scan1_kernel<<<sb, 256, 0, stream>>>(n_scan);
    scan2_kernel<<<1, 256, 0, stream>>>(sb);
    scan3_kernel<<<sb, 256, 0, stream>>>(n_scan);
    scatter_src_kernel<<<nblk, 256, 0, stream>>>(ei, w, E, n_nodes, nblk, NB);
    deg_kernel<<<NB, 256, 0, stream>>>(E, n_nodes, nblk, NB);

    // --- sort by dst, then bucket-local gather ---
    count_kernel<<<nblk, 256, 0, stream>>>(ei, E, n_nodes, nblk, NB, 1);
    scan1_kernel<<<sb, 256, 0, stream>>>(n_scan);
    scan2_kernel<<<1, 256, 0, stream>>>(sb);
    scan3_kernel<<<sb, 256, 0, stream>>>(n_scan);
    scatter_dst_kernel<<<nblk, 256, 0, stream>>>(ei, w, E, n_nodes, nblk, NB);
    gather_kernel<<<NB, 256, 0, stream>>>(x, E, n_nodes, nblk, NB);

    gates_kernel<<<(n_nodes + 7) / 8, 256, 0, stream>>>(
        x, Wx, bx, bh, wc, bg, lin_w, lin_b, out, n_nodes);
}

// Round 6
// 569.541 us; speedup vs baseline: 1.0848x; 1.0848x over previous
//
#include <hip/hip_runtime.h>

// LSTM-GCN single step from (H=0, C=0).
// Collapsed math: Fg gate dead (C_prev=0), cheb(H,..)=bh, peephole wc[0],wc[1] dead.
//
// R6: atomic-free bucket sort (no global atomics anywhere), re-granularized.
// R5 post-mortem: gather at 782 blocks = 3 blocks/CU = 21% occupancy,
// latency-bound (346 us). Now 32-node buckets -> 3125 blocks (8/CU,
// wave-slot-limited), unroll-8, merged src+dst sort passes, dinv prescaled
// into x. Only LDS atomics remain.

#define FDIM 32
#define MAX_N 100000
#define MAX_E 1600000
#define TILE 8192            // edges per sort tile (256 thr x 32)
#define NB_MAXB 3136         // max 32-node buckets (100000/32 -> 3125)
#define NBLK_MAX 196         // 1.6M / 8192
#define SCAN_TILE 2048       // scan1 elements per block (256 thr x 8)

__device__ float g_dinv[MAX_N];
__device__ float g_xs[MAX_N * FDIM];            // dinv[src] * x
__device__ int   g_tileh[2 * NB_MAXB * NBLK_MAX]; // [src bins | dst bins] x tile, bin-major
__device__ int   g_blk[1024];
__device__ int   g_total;                       // 2 * (valid edge count)
__device__ uint2 g_rec[2 * MAX_E];              // [src-sorted | dst-sorted] records
__device__ float g_tx1[MAX_N * FDIM];           // L_hat @ x

// ---- per-tile dual histogram (bin-major output) -----------------------------
__global__ __launch_bounds__(256) void count_kernel(const int* __restrict__ ei,
                                                    int E, int n_nodes, int nblk,
                                                    int NB) {
    __shared__ int hist[2 * NB_MAXB];           // 25 KB
    int nb2 = 2 * NB;
    for (int i = threadIdx.x; i < nb2; i += 256) hist[i] = 0;
    __syncthreads();
    int base = blockIdx.x * TILE;
    int lim  = min(TILE, E - base);
    for (int t = threadIdx.x; t < lim; t += 256) {
        int e = base + t;
        int s = ei[e], d = ei[E + e];
        if ((unsigned)s >= (unsigned)n_nodes || (unsigned)d >= (unsigned)n_nodes) continue;
        atomicAdd(&hist[s >> 5], 1);
        atomicAdd(&hist[NB + (d >> 5)], 1);
    }
    __syncthreads();
    for (int i = threadIdx.x; i < nb2; i += 256)
        g_tileh[i * nblk + blockIdx.x] = hist[i];   // uncoalesced but L2-resident
}

// ---- exclusive scan over g_tileh[0..n) --------------------------------------
__global__ __launch_bounds__(256) void scan1_kernel(int n) {
    __shared__ int sh[256];
    int tid = threadIdx.x;
    int base = blockIdx.x * SCAN_TILE + tid * 8;
    int v[8];
#pragma unroll
    for (int i = 0; i < 8; ++i) v[i] = (base + i < n) ? g_tileh[base + i] : 0;
    int tsum = 0;
#pragma unroll
    for (int i = 0; i < 8; ++i) tsum += v[i];
    sh[tid] = tsum;
    __syncthreads();
    for (int off = 1; off < 256; off <<= 1) {
        int t = (tid >= off) ? sh[tid - off] : 0;
        __syncthreads();
        sh[tid] += t;
        __syncthreads();
    }
    if (tid == 255) g_blk[blockIdx.x] = sh[255];
    int run = sh[tid] - tsum;
#pragma unroll
    for (int i = 0; i < 8; ++i) {
        if (base + i < n) g_tileh[base + i] = run;
        run += v[i];
    }
}

__global__ __launch_bounds__(256) void scan2_kernel(int nb) {   // nb <= 1024
    __shared__ int sh[256];
    int tid = threadIdx.x;
    int base = tid * 4;
    int v[4];
#pragma unroll
    for (int i = 0; i < 4; ++i) v[i] = (base + i < nb) ? g_blk[base + i] : 0;
    int tsum = v[0] + v[1] + v[2] + v[3];
    sh[tid] = tsum;
    __syncthreads();
    for (int off = 1; off < 256; off <<= 1) {
        int t = (tid >= off) ? sh[tid - off] : 0;
        __syncthreads();
        sh[tid] += t;
        __syncthreads();
    }
    if (tid == 255) g_total = sh[255];          // grand total = 2 * valid edges
    int run = sh[tid] - tsum;
#pragma unroll
    for (int i = 0; i < 4; ++i) {
        if (base + i < nb) g_blk[base + i] = run;
        run += v[i];
    }
}

__global__ __launch_bounds__(256) void scan3_kernel(int n) {
    int off = g_blk[blockIdx.x];
    int base = blockIdx.x * SCAN_TILE + threadIdx.x * 8;
#pragma unroll
    for (int i = 0; i < 8; ++i)
        if (base + i < n) g_tileh[base + i] += off;
}

// ---- scatter both sorts with LDS cursors (no global atomics) ----------------
__global__ __launch_bounds__(256) void scatter_kernel(const int* __restrict__ ei,
                                                      const float* __restrict__ w,
                                                      int E, int n_nodes, int nblk,
                                                      int NB) {
    __shared__ int cur[2 * NB_MAXB];            // 25 KB
    int nb2 = 2 * NB;
    for (int i = threadIdx.x; i < nb2; i += 256)
        cur[i] = g_tileh[i * nblk + blockIdx.x];
    __syncthreads();
    int base = blockIdx.x * TILE;
    int lim  = min(TILE, E - base);
    for (int t = threadIdx.x; t < lim; t += 256) {
        int e = base + t;
        int s = ei[e], d = ei[E + e];
        if ((unsigned)s >= (unsigned)n_nodes || (unsigned)d >= (unsigned)n_nodes) continue;
        unsigned wb = __float_as_uint((s == d) ? 0.f : w[e]);
        int pa = atomicAdd(&cur[s >> 5], 1);            // LDS atomic
        g_rec[pa] = make_uint2((unsigned)(s & 31), wb); // src-local, w
        int pb = atomicAdd(&cur[NB + (d >> 5)], 1);     // LDS atomic
        g_rec[pb] = make_uint2((unsigned)s | ((unsigned)(d & 31) << 17), wb);
    }
}

// ---- per-bucket degree + rsqrt (src-sorted section) -------------------------
__global__ __launch_bounds__(256) void deg_kernel(int n_nodes, int nblk, int NB) {
    __shared__ float degl[32];
    int bin = blockIdx.x, tid = threadIdx.x;
    if (tid < 32) degl[tid] = 0.f;
    __syncthreads();
    int start = g_tileh[bin * nblk];
    int end   = (bin + 1 < NB) ? g_tileh[(bin + 1) * nblk] : g_tileh[NB * nblk];
    for (int i = start + tid; i < end; i += 256) {
        uint2 r = g_rec[i];
        atomicAdd(&degl[r.x & 31], __uint_as_float(r.y));   // LDS atomic
    }
    __syncthreads();
    if (tid < 32) {
        int node = bin * 32 + tid;
        if (node < n_nodes) {
            float dg = degl[tid];
            g_dinv[node] = (dg > 0.f) ? rsqrtf(dg) : 0.f;
        }
    }
}

// ---- xs = dinv[node] * x ----------------------------------------------------
__global__ void xscale_kernel(const float* __restrict__ x, int n_nodes) {
    int i = blockIdx.x * blockDim.x + threadIdx.x;
    if (i < n_nodes * FDIM) g_xs[i] = x[i] * g_dinv[i >> 5];
}

// ---- per-bucket gather: tx1 = L_hat @ x (dst-sorted section) ----------------
__global__ __launch_bounds__(256) void gather_kernel(int n_nodes, int nblk, int NB) {
    __shared__ float acc[32 * FDIM];    // 4 KB
    __shared__ float dneg[32];
    int tid = threadIdx.x, bin = blockIdx.x;
    for (int i = tid; i < 32 * FDIM; i += 256) acc[i] = 0.f;
    if (tid < 32) {
        int node = bin * 32 + tid;
        dneg[tid] = (node < n_nodes) ? -g_dinv[node] : 0.f;
    }
    __syncthreads();
    int start = g_tileh[(NB + bin) * nblk];
    int end   = (bin + 1 < NB) ? g_tileh[(NB + bin + 1) * nblk] : g_total;
    int hw = tid >> 5, f = tid & 31;
    int i = start + hw;
    for (; i + 56 < end; i += 64) {     // 8 half-waves x unroll-8
        uint2 r[8];
#pragma unroll
        for (int j = 0; j < 8; ++j) r[j] = g_rec[i + 8 * j];
        float xv[8];
#pragma unroll
        for (int j = 0; j < 8; ++j) xv[j] = g_xs[(r[j].x & 0x1FFFF) * FDIM + f];
#pragma unroll
        for (int j = 0; j < 8; ++j) {
            int dl = r[j].x >> 17;
            atomicAdd(&acc[dl * FDIM + f],
                      dneg[dl] * __uint_as_float(r[j].y) * xv[j]);   // LDS atomic
        }
    }
    for (; i < end; i += 8) {
        uint2 r = g_rec[i];
        int dl = r.x >> 17;
        atomicAdd(&acc[dl * FDIM + f],
                  dneg[dl] * __uint_as_float(r.y) * g_xs[(r.x & 0x1FFFF) * FDIM + f]);
    }
    __syncthreads();
    int nodeb = bin * 32;
    for (int j = tid; j < 32 * FDIM; j += 256) {
        int node = nodeb + (j >> 5);
        if (node < n_nodes) g_tx1[node * FDIM + (j & 31)] = acc[j];
    }
}

// ---- gates + epilogue (unchanged; correctness-proven) -----------------------
__global__ __launch_bounds__(256) void gates_kernel(
    const float* __restrict__ x,
    const float* __restrict__ Wx, const float* __restrict__ bx,
    const float* __restrict__ bh, const float* __restrict__ wc,
    const float* __restrict__ bg, const float* __restrict__ lin_w,
    const float* __restrict__ lin_b, float* __restrict__ out, int n_nodes) {
    __shared__ float Ws[3 * 2048];      // gates {i,c,o} x K=2 x 32x32
    __shared__ float xs[8 * FDIM];
    __shared__ float ts[8 * FDIM];

    for (int idx = threadIdx.x; idx < 2048; idx += 256) {
        Ws[idx]          = Wx[0 * 2048 + idx];
        Ws[2048 + idx]   = Wx[2 * 2048 + idx];
        Ws[4096 + idx]   = Wx[3 * 2048 + idx];
    }
    int node0 = blockIdx.x * 8;
    {
        int n = node0 + (threadIdx.x >> 5);
        int f = threadIdx.x & 31;
        if (n < n_nodes) {
            xs[threadIdx.x] = x[n * FDIM + f];
            ts[threadIdx.x] = g_tx1[n * FDIM + f];
        }
    }
    __syncthreads();

    int ln = threadIdx.x >> 5;
    int j  = threadIdx.x & 31;
    int n  = node0 + ln;
    if (n >= n_nodes) return;

    const float* xr = &xs[ln * FDIM];
    const float* tr = &ts[ln * FDIM];
    float acc_i = 0.f, acc_c = 0.f, acc_o = 0.f;
#pragma unroll
    for (int k = 0; k < 32; ++k) {
        float xv = xr[k], tv = tr[k];
        int o0 = k * 32 + j;
        acc_i += xv * Ws[o0]          + tv * Ws[1024 + o0];
        acc_c += xv * Ws[2048 + o0]   + tv * Ws[3072 + o0];
        acc_o += xv * Ws[4096 + o0]   + tv * Ws[5120 + o0];
    }
    float bi = bx[0 * 32 + j] + bh[0 * 32 + j] + bg[0 * 32 + j];
    float bc = bx[2 * 32 + j] + bh[2 * 32 + j] + bg[2 * 32 + j];
    float bo = bx[3 * 32 + j] + bh[3 * 32 + j] + bg[3 * 32 + j];

    float I = 1.f / (1.f + __expf(-(acc_i + bi)));
    float T = tanhf(acc_c + bc);
    float C = I * T;                                    // Fg*C_prev = 0
    float O = 1.f / (1.f + __expf(-(acc_o + bo + wc[2 * 32 + j] * C)));
    float H = O * tanhf(C);
    float r = fmaxf(H, 0.f) * lin_w[j];
#pragma unroll
    for (int m = 16; m > 0; m >>= 1) r += __shfl_xor(r, m, 32);
    if (j == 0) out[n] = r + lin_b[0];
}

extern "C" void kernel_launch(void* const* d_in, const int* in_sizes, int n_in,
                              void* d_out, int out_size, void* d_ws, size_t ws_size,
                              hipStream_t stream) {
    const float* x     = (const float*)d_in[0];
    const int*   ei    = (const int*)d_in[1];      // int32 on device
    const float* w     = (const float*)d_in[2];
    const float* Wx    = (const float*)d_in[3];
    const float* bx    = (const float*)d_in[4];
    // d_in[5] = Wh: unused (H=0)
    const float* bh    = (const float*)d_in[6];
    const float* wc    = (const float*)d_in[7];
    const float* bg    = (const float*)d_in[8];
    const float* lin_w = (const float*)d_in[9];
    const float* lin_b = (const float*)d_in[10];
    float*       out   = (float*)d_out;

    int n_nodes = in_sizes[0] / FDIM;
    if (n_nodes > MAX_N) n_nodes = MAX_N;
    int E = in_sizes[2];
    if (E > MAX_E) E = MAX_E;

    const int nblk = (E + TILE - 1) / TILE;          // 196
    const int NB   = (n_nodes + 31) >> 5;            // 3125
    const int n_scan = 2 * NB * nblk;                // 1,225,000
    const int sb   = (n_scan + SCAN_TILE - 1) / SCAN_TILE;   // 599 (<=1024)

    count_kernel<<<nblk, 256, 0, stream>>>(ei, E, n_nodes, nblk, NB);
    scan1_kernel<<<sb, 256, 0, stream>>>(n_scan);
    scan2_kernel<<<1, 256, 0, stream>>>(sb);
    scan3_kernel<<<sb, 256, 0, stream>>>(n_scan);
    scatter_kernel<<<nblk, 256, 0, stream>>>(ei, w, E, n_nodes, nblk, NB);
    deg_kernel<<<NB, 256, 0, stream>>>(n_nodes, nblk, NB);
    xscale_kernel<<<(n_nodes * FDIM + 255) / 256, 256, 0, stream>>>(x, n_nodes);
    gather_kernel<<<NB, 256, 0, stream>>>(n_nodes, nblk, NB);
    gates_kernel<<<(n_nodes + 7) / 8, 256, 0, stream>>>(
        x, Wx, bx, bh, wc, bg, lin_w, lin_b, out, n_nodes);
}